// Round 1
// baseline (11935.267 us; speedup 1.0000x reference)
//
#include <hip/hip_runtime.h>
#include <hip/hip_bf16.h>
#include <math.h>

#define HD 128      // hidden features
#define EFD 16      // edge features
#define TE 32       // edges per block
#define TN 32       // nodes per block

__device__ __forceinline__ float silu_f(float x) {
    return x / (1.f + __expf(-x));
}

// ---------------------------------------------------------------------------
// Edge kernel: per 32-edge tile
//   f = [h[src] (128), h[dst] (128), radial (1), a (16)]  (MF = 273)
//   c  = silu(silu(f@Wc1+bc1)@Wc2+bc2); scale = c@Wc3
//   msg_x = scale * diff / (sqrt(radial+1e-5)+1)      -> atomic into out_x
//   m  = silu(silu(f@We1+be1)@We2+be2)
//   att = sigmoid(m@Watt+batt); msg_h = att*m         -> atomic into out_h
// Thread layout: e = tid>>3 (32 edges), jb = (tid&7)*16 (16 features each)
// ---------------------------------------------------------------------------
__global__ __launch_bounds__(256) void edge_kernel(
    const int* __restrict__ src, const int* __restrict__ dst,
    const float* __restrict__ h, const float* __restrict__ coords,
    const float* __restrict__ a,
    const float* __restrict__ Wc1, const float* __restrict__ bc1,
    const float* __restrict__ Wc2, const float* __restrict__ bc2,
    const float* __restrict__ Wc3,
    const float* __restrict__ We1, const float* __restrict__ be1,
    const float* __restrict__ We2, const float* __restrict__ be2,
    const float* __restrict__ Watt, const float* __restrict__ batt,
    float* __restrict__ out_h, float* __restrict__ out_x)
{
    __shared__ float fh[TE][257];      // h[src] at k<128, h[dst] at 128..255 (stride 257: conflict-free rows)
    __shared__ float a_s[TE][EFD];
    __shared__ float radial_s[TE];
    __shared__ float diff_s[TE][3];
    __shared__ int   src_s[TE], dst_s[TE];
    __shared__ float buf[TE][132];     // layer-1 outputs (reused by both MLPs)

    const int tid = threadIdx.x;
    const int e0  = blockIdx.x * TE;

    if (tid < TE) {
        src_s[tid] = src[e0 + tid];
        dst_s[tid] = dst[e0 + tid];
    }
    __syncthreads();

    // stage h[src] / h[dst] rows (coalesced: 256 consecutive idx = one edge row)
    for (int idx = tid; idx < TE * 256; idx += 256) {
        const int e = idx >> 8, k = idx & 255;
        fh[e][k] = (k < HD) ? h[(size_t)src_s[e] * HD + k]
                            : h[(size_t)dst_s[e] * HD + (k - HD)];
    }
    for (int idx = tid; idx < TE * EFD; idx += 256) {
        const int e = idx >> 4, t = idx & 15;
        a_s[e][t] = a[(size_t)(e0 + e) * EFD + t];
    }
    if (tid < TE) {
        const int s = src_s[tid], d = dst_s[tid];
        const float dx = coords[s*3+0] - coords[d*3+0];
        const float dy = coords[s*3+1] - coords[d*3+1];
        const float dz = coords[s*3+2] - coords[d*3+2];
        diff_s[tid][0] = dx; diff_s[tid][1] = dy; diff_s[tid][2] = dz;
        radial_s[tid] = dx*dx + dy*dy + dz*dz;
    }
    __syncthreads();

    const int e  = tid >> 3;
    const int jb = (tid & 7) * 16;

    float acc[16];

    // ---- c1 = silu(f @ Wc1 + bc1) -> buf -------------------------------
    {
        const float rad = radial_s[e];
        #pragma unroll
        for (int i = 0; i < 16; ++i)
            acc[i] = bc1[jb + i] + rad * Wc1[256 * HD + jb + i];
        #pragma unroll
        for (int t = 0; t < EFD; ++t) {
            const float av = a_s[e][t];
            const float4* wr = (const float4*)(Wc1 + (257 + t) * HD + jb);
            #pragma unroll
            for (int q = 0; q < 4; ++q) {
                const float4 w = wr[q];
                acc[4*q+0] += av * w.x; acc[4*q+1] += av * w.y;
                acc[4*q+2] += av * w.z; acc[4*q+3] += av * w.w;
            }
        }
        #pragma unroll 4
        for (int k = 0; k < 256; ++k) {
            const float fk = fh[e][k];
            const float4* wr = (const float4*)(Wc1 + k * HD + jb);
            #pragma unroll
            for (int q = 0; q < 4; ++q) {
                const float4 w = wr[q];
                acc[4*q+0] += fk * w.x; acc[4*q+1] += fk * w.y;
                acc[4*q+2] += fk * w.z; acc[4*q+3] += fk * w.w;
            }
        }
        #pragma unroll
        for (int i = 0; i < 16; ++i) buf[e][jb + i] = silu_f(acc[i]);
    }
    __syncthreads();

    // ---- c2 = silu(c1 @ Wc2 + bc2) (regs only); scale = c2 @ Wc3 -------
    {
        #pragma unroll
        for (int i = 0; i < 16; ++i) acc[i] = bc2[jb + i];
        #pragma unroll 4
        for (int k = 0; k < HD; ++k) {
            const float fk = buf[e][k];
            const float4* wr = (const float4*)(Wc2 + k * HD + jb);
            #pragma unroll
            for (int q = 0; q < 4; ++q) {
                const float4 w = wr[q];
                acc[4*q+0] += fk * w.x; acc[4*q+1] += fk * w.y;
                acc[4*q+2] += fk * w.z; acc[4*q+3] += fk * w.w;
            }
        }
        float part = 0.f;
        #pragma unroll
        for (int i = 0; i < 16; ++i) part += silu_f(acc[i]) * Wc3[jb + i];
        part += __shfl_xor(part, 1);
        part += __shfl_xor(part, 2);
        part += __shfl_xor(part, 4);   // all 8 lanes of the edge-group hold scale
        const float rad  = radial_s[e];
        const float rinv = 1.f / (sqrtf(rad + 1e-5f) + 1.f);
        const int d = tid & 7;
        if (d < 3)
            atomicAdd(&out_x[(size_t)dst_s[e] * 3 + d], part * diff_s[e][d] * rinv);
    }
    __syncthreads();   // all reads of buf done before e1 overwrites it

    // ---- e1 = silu(f @ We1 + be1) -> buf -------------------------------
    {
        const float rad = radial_s[e];
        #pragma unroll
        for (int i = 0; i < 16; ++i)
            acc[i] = be1[jb + i] + rad * We1[256 * HD + jb + i];
        #pragma unroll
        for (int t = 0; t < EFD; ++t) {
            const float av = a_s[e][t];
            const float4* wr = (const float4*)(We1 + (257 + t) * HD + jb);
            #pragma unroll
            for (int q = 0; q < 4; ++q) {
                const float4 w = wr[q];
                acc[4*q+0] += av * w.x; acc[4*q+1] += av * w.y;
                acc[4*q+2] += av * w.z; acc[4*q+3] += av * w.w;
            }
        }
        #pragma unroll 4
        for (int k = 0; k < 256; ++k) {
            const float fk = fh[e][k];
            const float4* wr = (const float4*)(We1 + k * HD + jb);
            #pragma unroll
            for (int q = 0; q < 4; ++q) {
                const float4 w = wr[q];
                acc[4*q+0] += fk * w.x; acc[4*q+1] += fk * w.y;
                acc[4*q+2] += fk * w.z; acc[4*q+3] += fk * w.w;
            }
        }
        #pragma unroll
        for (int i = 0; i < 16; ++i) buf[e][jb + i] = silu_f(acc[i]);
    }
    __syncthreads();

    // ---- msg = silu(e1 @ We2 + be2); att-gate; atomic scatter ----------
    {
        #pragma unroll
        for (int i = 0; i < 16; ++i) acc[i] = be2[jb + i];
        #pragma unroll 4
        for (int k = 0; k < HD; ++k) {
            const float fk = buf[e][k];
            const float4* wr = (const float4*)(We2 + k * HD + jb);
            #pragma unroll
            for (int q = 0; q < 4; ++q) {
                const float4 w = wr[q];
                acc[4*q+0] += fk * w.x; acc[4*q+1] += fk * w.y;
                acc[4*q+2] += fk * w.z; acc[4*q+3] += fk * w.w;
            }
        }
        float msg[16];
        float part = 0.f;
        #pragma unroll
        for (int i = 0; i < 16; ++i) {
            msg[i] = silu_f(acc[i]);
            part += msg[i] * Watt[jb + i];
        }
        part += __shfl_xor(part, 1);
        part += __shfl_xor(part, 2);
        part += __shfl_xor(part, 4);
        const float att = 1.f / (1.f + __expf(-(part + batt[0])));
        float* dsth = out_h + (size_t)dst_s[e] * HD + jb;
        #pragma unroll
        for (int i = 0; i < 16; ++i) atomicAdd(&dsth[i], att * msg[i]);
    }
}

// ---------------------------------------------------------------------------
// Node kernel: reads aggregates from d_out (in place), computes
//   h_out = h + silu([h, h_agg] @ Wn1 + bn1) @ Wn2 + bn2
//   coords_out = coords + x_agg
// ---------------------------------------------------------------------------
__global__ __launch_bounds__(256) void node_kernel(
    const float* __restrict__ h, const float* __restrict__ coords,
    const float* __restrict__ Wn1, const float* __restrict__ bn1,
    const float* __restrict__ Wn2, const float* __restrict__ bn2,
    float* __restrict__ out_h, float* __restrict__ out_x)
{
    __shared__ float hh[TN][257];      // [h (128), h_agg (128)]
    __shared__ float buf[TN][132];

    const int tid = threadIdx.x;
    const int n0  = blockIdx.x * TN;

    for (int idx = tid; idx < TN * 256; idx += 256) {
        const int n = idx >> 8, k = idx & 255;
        hh[n][k] = (k < HD) ? h[(size_t)(n0 + n) * HD + k]
                            : out_h[(size_t)(n0 + n) * HD + (k - HD)];  // aggregate
    }
    __syncthreads();

    // coords_out = coords + x_agg (independent of the rest)
    if (tid < TN * 3) {
        const int n = tid / 3, d = tid % 3;
        const size_t gi = (size_t)(n0 + n) * 3 + d;
        out_x[gi] = out_x[gi] + coords[gi];
    }

    const int n  = tid >> 3;
    const int jb = (tid & 7) * 16;

    float acc[16];
    #pragma unroll
    for (int i = 0; i < 16; ++i) acc[i] = bn1[jb + i];
    #pragma unroll 4
    for (int k = 0; k < 256; ++k) {
        const float fk = hh[n][k];
        const float4* wr = (const float4*)(Wn1 + k * HD + jb);
        #pragma unroll
        for (int q = 0; q < 4; ++q) {
            const float4 w = wr[q];
            acc[4*q+0] += fk * w.x; acc[4*q+1] += fk * w.y;
            acc[4*q+2] += fk * w.z; acc[4*q+3] += fk * w.w;
        }
    }
    #pragma unroll
    for (int i = 0; i < 16; ++i) buf[n][jb + i] = silu_f(acc[i]);
    __syncthreads();

    #pragma unroll
    for (int i = 0; i < 16; ++i) acc[i] = bn2[jb + i];
    #pragma unroll 4
    for (int k = 0; k < HD; ++k) {
        const float fk = buf[n][k];
        const float4* wr = (const float4*)(Wn2 + k * HD + jb);
        #pragma unroll
        for (int q = 0; q < 4; ++q) {
            const float4 w = wr[q];
            acc[4*q+0] += fk * w.x; acc[4*q+1] += fk * w.y;
            acc[4*q+2] += fk * w.z; acc[4*q+3] += fk * w.w;
        }
    }
    float* oh = out_h + (size_t)(n0 + n) * HD + jb;
    #pragma unroll
    for (int i = 0; i < 16; ++i) oh[i] = hh[n][jb + i] + acc[i];   // h + nh
}

extern "C" void kernel_launch(void* const* d_in, const int* in_sizes, int n_in,
                              void* d_out, int out_size, void* d_ws, size_t ws_size,
                              hipStream_t stream)
{
    const int*   src    = (const int*)  d_in[0];
    const int*   dst    = (const int*)  d_in[1];
    const float* h      = (const float*)d_in[2];
    const float* coords = (const float*)d_in[3];
    const float* a      = (const float*)d_in[4];
    const float* Wc1    = (const float*)d_in[5];
    const float* bc1    = (const float*)d_in[6];
    const float* Wc2    = (const float*)d_in[7];
    const float* bc2    = (const float*)d_in[8];
    const float* Wc3    = (const float*)d_in[9];
    const float* We1    = (const float*)d_in[10];
    const float* be1    = (const float*)d_in[11];
    const float* We2    = (const float*)d_in[12];
    const float* be2    = (const float*)d_in[13];
    const float* Watt   = (const float*)d_in[14];
    const float* batt   = (const float*)d_in[15];
    const float* Wn1    = (const float*)d_in[16];
    const float* bn1    = (const float*)d_in[17];
    const float* Wn2    = (const float*)d_in[18];
    const float* bn2    = (const float*)d_in[19];

    const int E = in_sizes[0];
    const int N = in_sizes[2] / HD;

    float* out_h = (float*)d_out;
    float* out_x = out_h + (size_t)N * HD;

    // aggregates accumulate directly into d_out; zero it first (on-stream)
    hipMemsetAsync(d_out, 0, (size_t)out_size * sizeof(float), stream);

    edge_kernel<<<dim3(E / TE), dim3(256), 0, stream>>>(
        src, dst, h, coords, a,
        Wc1, bc1, Wc2, bc2, Wc3,
        We1, be1, We2, be2, Watt, batt,
        out_h, out_x);

    node_kernel<<<dim3(N / TN), dim3(256), 0, stream>>>(
        h, coords, Wn1, bn1, Wn2, bn2, out_h, out_x);
}

// Round 3
// 730.674 us; speedup vs baseline: 16.3346x; 16.3346x over previous
//
#include <hip/hip_runtime.h>
#include <math.h>

#define HD   128     // hidden features
#define EFD  16      // edge features
#define KP   288     // layer-1 K padded (273 -> 288 = 9*32)
#define MT   64      // edges / nodes per block
#define LPF  296     // LDS pitch (ushort) for f tile   (592 B -> uniform banks)
#define LPA  264     // LDS pitch (ushort) for node A tile (528 B)
#define LPC  136     // LDS pitch (ushort) for layer-1 out tile (272 B)

#define W1SZ (128 * KP)    // one transposed layer-1 weight panel
#define W2SZ (128 * 128)
// ws layout (ushort elems): Wc1t | We1t | Wc2t | We2t | Wn1t(128x256) | Wn2t
#define O_WE1 (W1SZ)
#define O_WC2 (2 * W1SZ)
#define O_WE2 (2 * W1SZ + W2SZ)
#define O_WN1 (2 * W1SZ + 2 * W2SZ)
#define O_WN2 (2 * W1SZ + 2 * W2SZ + 128 * 256)
#define WS_ELEMS (O_WN2 + W2SZ)

typedef __attribute__((ext_vector_type(8))) short short8;
typedef __attribute__((ext_vector_type(4))) float f32x4;

__device__ __forceinline__ unsigned short f2bf(float x) {
    union { float f; unsigned u; } v; v.f = x;
    unsigned r = v.u + 0x7fffu + ((v.u >> 16) & 1u);   // round-to-nearest-even
    return (unsigned short)(r >> 16);
}
__device__ __forceinline__ float silu_f(float x) { return x / (1.f + __expf(-x)); }

// ---------------------------------------------------------------------------
// Weight prep: fp32 [K][128] -> bf16 transposed [128][Kpad] panels in ws
// ---------------------------------------------------------------------------
__global__ __launch_bounds__(256) void prep_weights(
    const float* __restrict__ Wc1, const float* __restrict__ We1,
    const float* __restrict__ Wc2, const float* __restrict__ We2,
    const float* __restrict__ Wn1, const float* __restrict__ Wn2,
    unsigned short* __restrict__ ws)
{
    int idx = blockIdx.x * 256 + threadIdx.x;
    if (idx < W1SZ) {                       // Wc1t
        int c = idx / KP, k = idx % KP;
        ws[idx] = (k < 273) ? f2bf(Wc1[k * HD + c]) : (unsigned short)0;
        return;
    }
    idx -= W1SZ;
    if (idx < W1SZ) {                       // We1t
        int c = idx / KP, k = idx % KP;
        ws[O_WE1 + idx] = (k < 273) ? f2bf(We1[k * HD + c]) : (unsigned short)0;
        return;
    }
    idx -= W1SZ;
    if (idx < W2SZ) {                       // Wc2t
        int c = idx / HD, k = idx % HD;
        ws[O_WC2 + idx] = f2bf(Wc2[k * HD + c]);
        return;
    }
    idx -= W2SZ;
    if (idx < W2SZ) {                       // We2t
        int c = idx / HD, k = idx % HD;
        ws[O_WE2 + idx] = f2bf(We2[k * HD + c]);
        return;
    }
    idx -= W2SZ;
    if (idx < 128 * 256) {                  // Wn1t [128][256]
        int c = idx / 256, k = idx % 256;
        ws[O_WN1 + idx] = f2bf(Wn1[k * HD + c]);
        return;
    }
    idx -= 128 * 256;
    if (idx < W2SZ) {                       // Wn2t
        int c = idx / HD, k = idx % HD;
        ws[O_WN2 + idx] = f2bf(Wn2[k * HD + c]);
    }
}

// ---------------------------------------------------------------------------
// Edge kernel (MFMA): 64 edges/block, 4 waves, wave = 16 edges x 128 feats
// ---------------------------------------------------------------------------
__global__ __launch_bounds__(256) void edge_kernel(
    const int* __restrict__ src, const int* __restrict__ dst,
    const float* __restrict__ h, const float* __restrict__ coords,
    const float* __restrict__ a,
    const float* __restrict__ bc1, const float* __restrict__ bc2,
    const float* __restrict__ Wc3,
    const float* __restrict__ be1, const float* __restrict__ be2,
    const float* __restrict__ Watt, const float* __restrict__ batt,
    const unsigned short* __restrict__ ws,
    float* __restrict__ out_h, float* __restrict__ out_x)
{
    __shared__ __align__(16) unsigned short fsh[MT][LPF];   // f tile, bf16
    __shared__ __align__(16) unsigned short csh[MT][LPC];   // layer-1 out, bf16
    __shared__ float diff_s[MT][3];
    __shared__ float rinv_s[MT];
    __shared__ int   src_s[MT], dst_s[MT];

    const int tid = threadIdx.x;
    const int e0  = blockIdx.x * MT;

    if (tid < MT) {
        const int s = src[e0 + tid], d = dst[e0 + tid];
        src_s[tid] = s; dst_s[tid] = d;
        const float dx = coords[(size_t)s*3+0] - coords[(size_t)d*3+0];
        const float dy = coords[(size_t)s*3+1] - coords[(size_t)d*3+1];
        const float dz = coords[(size_t)s*3+2] - coords[(size_t)d*3+2];
        diff_s[tid][0] = dx; diff_s[tid][1] = dy; diff_s[tid][2] = dz;
        const float rad = dx*dx + dy*dy + dz*dz;
        rinv_s[tid] = 1.f / (sqrtf(rad + 1e-5f) + 1.f);
        fsh[tid][256] = f2bf(rad);                       // radial feature col
    }
    __syncthreads();

    // gather h[src] | h[dst] rows as bf16 (float4 loads, 8B LDS stores)
    #pragma unroll
    for (int it = 0; it < 16; ++it) {
        const int idx = it * 256 + tid;
        const int e = idx >> 6, q = idx & 63;            // q: float4 slot (0..63)
        const float* base = (q < 32)
            ? h + (size_t)src_s[e] * HD + q * 4
            : h + (size_t)dst_s[e] * HD + (q - 32) * 4;
        const float4 v = *(const float4*)base;
        union { unsigned short us[4]; uint2 u2; } p;
        p.us[0] = f2bf(v.x); p.us[1] = f2bf(v.y);
        p.us[2] = f2bf(v.z); p.us[3] = f2bf(v.w);
        *(uint2*)&fsh[e][q * 4] = p.u2;                  // cols q*4 .. q*4+3
    }
    // a features -> cols 257..272 ; zero pad cols 273..287
    #pragma unroll
    for (int it = 0; it < 4; ++it) {
        const int id = it * 256 + tid;
        const int e = id >> 4, t = id & 15;
        if (t < 15) fsh[e][273 + t] = 0;
    }
    #pragma unroll
    for (int it = 0; it < 4; ++it) {
        const int id = it * 256 + tid;
        const int e = id >> 4, t = id & 15;
        fsh[e][257 + t] = f2bf(a[(size_t)(e0 + e) * EFD + t]);
    }
    __syncthreads();

    const int lane = tid & 63;
    const int w    = tid >> 6;
    const int er0  = w * 16;            // this wave's edge rows
    const int col  = lane & 15;         // output-feature col within 16-tile
    const int kg   = lane >> 4;         // k-group (0..3)

    const unsigned short* Wc1t = ws;
    const unsigned short* We1t = ws + O_WE1;
    const unsigned short* Wc2t = ws + O_WC2;
    const unsigned short* We2t = ws + O_WE2;

    const f32x4 zero = {0.f, 0.f, 0.f, 0.f};
    f32x4 acc[8];

    // ================= coord-MLP =================
    #pragma unroll
    for (int n = 0; n < 8; ++n) acc[n] = zero;
    #pragma unroll
    for (int kc = 0; kc < 9; ++kc) {
        const short8 af = *(const short8*)&fsh[er0 + col][kc * 32 + kg * 8];
        #pragma unroll
        for (int n = 0; n < 8; ++n) {
            const short8 bf = *(const short8*)&Wc1t[(size_t)(n*16 + col) * KP + kc * 32 + kg * 8];
            acc[n] = __builtin_amdgcn_mfma_f32_16x16x32_bf16(af, bf, acc[n], 0, 0, 0);
        }
    }
    #pragma unroll
    for (int n = 0; n < 8; ++n) {
        const float b = bc1[n*16 + col];
        #pragma unroll
        for (int i = 0; i < 4; ++i)
            csh[er0 + kg*4 + i][n*16 + col] = f2bf(silu_f(acc[n][i] + b));
    }
    // layer 2 (K=128) — reads only this wave's rows (no barrier needed)
    #pragma unroll
    for (int n = 0; n < 8; ++n) acc[n] = zero;
    #pragma unroll
    for (int kc = 0; kc < 4; ++kc) {
        const short8 af = *(const short8*)&csh[er0 + col][kc * 32 + kg * 8];
        #pragma unroll
        for (int n = 0; n < 8; ++n) {
            const short8 bf = *(const short8*)&Wc2t[(size_t)(n*16 + col) * HD + kc * 32 + kg * 8];
            acc[n] = __builtin_amdgcn_mfma_f32_16x16x32_bf16(af, bf, acc[n], 0, 0, 0);
        }
    }
    {   // scale = c2 . Wc3 ; msg_x scatter
        float part[4] = {0.f, 0.f, 0.f, 0.f};
        #pragma unroll
        for (int n = 0; n < 8; ++n) {
            const float b  = bc2[n*16 + col];
            const float w3 = Wc3[n*16 + col];
            #pragma unroll
            for (int i = 0; i < 4; ++i) part[i] += silu_f(acc[n][i] + b) * w3;
        }
        #pragma unroll
        for (int m = 1; m < 16; m <<= 1) {
            #pragma unroll
            for (int i = 0; i < 4; ++i) part[i] += __shfl_xor(part[i], m);
        }
        if (col < 3) {
            #pragma unroll
            for (int i = 0; i < 4; ++i) {
                const int e = er0 + kg*4 + i;
                atomicAdd(&out_x[(size_t)dst_s[e] * 3 + col],
                          part[i] * diff_s[e][col] * rinv_s[e]);
            }
        }
    }

    // ================= edge-MLP =================
    #pragma unroll
    for (int n = 0; n < 8; ++n) acc[n] = zero;
    #pragma unroll
    for (int kc = 0; kc < 9; ++kc) {
        const short8 af = *(const short8*)&fsh[er0 + col][kc * 32 + kg * 8];
        #pragma unroll
        for (int n = 0; n < 8; ++n) {
            const short8 bf = *(const short8*)&We1t[(size_t)(n*16 + col) * KP + kc * 32 + kg * 8];
            acc[n] = __builtin_amdgcn_mfma_f32_16x16x32_bf16(af, bf, acc[n], 0, 0, 0);
        }
    }
    #pragma unroll
    for (int n = 0; n < 8; ++n) {
        const float b = be1[n*16 + col];
        #pragma unroll
        for (int i = 0; i < 4; ++i)
            csh[er0 + kg*4 + i][n*16 + col] = f2bf(silu_f(acc[n][i] + b));
    }
    #pragma unroll
    for (int n = 0; n < 8; ++n) acc[n] = zero;
    #pragma unroll
    for (int kc = 0; kc < 4; ++kc) {
        const short8 af = *(const short8*)&csh[er0 + col][kc * 32 + kg * 8];
        #pragma unroll
        for (int n = 0; n < 8; ++n) {
            const short8 bf = *(const short8*)&We2t[(size_t)(n*16 + col) * HD + kc * 32 + kg * 8];
            acc[n] = __builtin_amdgcn_mfma_f32_16x16x32_bf16(af, bf, acc[n], 0, 0, 0);
        }
    }
    {   // att = sigmoid(msg . Watt + batt) ; gated scatter to out_h
        float msg[8][4];
        float pa[4] = {0.f, 0.f, 0.f, 0.f};
        #pragma unroll
        for (int n = 0; n < 8; ++n) {
            const float b  = be2[n*16 + col];
            const float wa = Watt[n*16 + col];
            #pragma unroll
            for (int i = 0; i < 4; ++i) {
                const float v = silu_f(acc[n][i] + b);
                msg[n][i] = v;
                pa[i] += v * wa;
            }
        }
        #pragma unroll
        for (int m = 1; m < 16; m <<= 1) {
            #pragma unroll
            for (int i = 0; i < 4; ++i) pa[i] += __shfl_xor(pa[i], m);
        }
        const float bt = batt[0];
        #pragma unroll
        for (int i = 0; i < 4; ++i) {
            const int e   = er0 + kg*4 + i;
            const float at = 1.f / (1.f + __expf(-(pa[i] + bt)));
            float* dsth = out_h + (size_t)dst_s[e] * HD;
            #pragma unroll
            for (int n = 0; n < 8; ++n)
                atomicAdd(&dsth[n*16 + col], at * msg[n][i]);
        }
    }
}

// ---------------------------------------------------------------------------
// Node kernel (MFMA): h_out = h + silu([h,h_agg]@Wn1+bn1)@Wn2+bn2
// ---------------------------------------------------------------------------
__global__ __launch_bounds__(256) void node_kernel(
    const float* __restrict__ h, const float* __restrict__ coords,
    const float* __restrict__ bn1, const float* __restrict__ bn2,
    const unsigned short* __restrict__ ws,
    float* __restrict__ out_h, float* __restrict__ out_x)
{
    __shared__ __align__(16) unsigned short ash[MT][LPA];   // [h | h_agg] bf16
    __shared__ __align__(16) unsigned short csh[MT][LPC];

    const int tid = threadIdx.x;
    const int n0  = blockIdx.x * MT;

    #pragma unroll
    for (int it = 0; it < 16; ++it) {
        const int idx = it * 256 + tid;
        const int e = idx >> 6, q = idx & 63;
        const float* base = (q < 32)
            ? h     + (size_t)(n0 + e) * HD + q * 4
            : out_h + (size_t)(n0 + e) * HD + (q - 32) * 4;   // h_agg
        const float4 v = *(const float4*)base;
        union { unsigned short us[4]; uint2 u2; } p;
        p.us[0] = f2bf(v.x); p.us[1] = f2bf(v.y);
        p.us[2] = f2bf(v.z); p.us[3] = f2bf(v.w);
        *(uint2*)&ash[e][q * 4] = p.u2;
    }
    __syncthreads();

    // coords_out = coords + x_agg
    if (tid < MT * 3) {
        const int n = tid / 3, d = tid % 3;
        const size_t gi = (size_t)(n0 + n) * 3 + d;
        out_x[gi] += coords[gi];
    }

    const int lane = tid & 63;
    const int w    = tid >> 6;
    const int er0  = w * 16;
    const int col  = lane & 15;
    const int kg   = lane >> 4;

    const unsigned short* Wn1t = ws + O_WN1;
    const unsigned short* Wn2t = ws + O_WN2;

    const f32x4 zero = {0.f, 0.f, 0.f, 0.f};
    f32x4 acc[8];

    #pragma unroll
    for (int n = 0; n < 8; ++n) acc[n] = zero;
    #pragma unroll
    for (int kc = 0; kc < 8; ++kc) {
        const short8 af = *(const short8*)&ash[er0 + col][kc * 32 + kg * 8];
        #pragma unroll
        for (int n = 0; n < 8; ++n) {
            const short8 bf = *(const short8*)&Wn1t[(size_t)(n*16 + col) * 256 + kc * 32 + kg * 8];
            acc[n] = __builtin_amdgcn_mfma_f32_16x16x32_bf16(af, bf, acc[n], 0, 0, 0);
        }
    }
    #pragma unroll
    for (int n = 0; n < 8; ++n) {
        const float b = bn1[n*16 + col];
        #pragma unroll
        for (int i = 0; i < 4; ++i)
            csh[er0 + kg*4 + i][n*16 + col] = f2bf(silu_f(acc[n][i] + b));
    }
    #pragma unroll
    for (int n = 0; n < 8; ++n) acc[n] = zero;
    #pragma unroll
    for (int kc = 0; kc < 4; ++kc) {
        const short8 af = *(const short8*)&csh[er0 + col][kc * 32 + kg * 8];
        #pragma unroll
        for (int n = 0; n < 8; ++n) {
            const short8 bf = *(const short8*)&Wn2t[(size_t)(n*16 + col) * HD + kc * 32 + kg * 8];
            acc[n] = __builtin_amdgcn_mfma_f32_16x16x32_bf16(af, bf, acc[n], 0, 0, 0);
        }
    }
    // epilogue: h (fp32 reload, exact residual) + nh + bn2 -> overwrite out_h
    #pragma unroll
    for (int i = 0; i < 4; ++i) {
        const int node = n0 + er0 + kg*4 + i;
        const float* hr = h     + (size_t)node * HD;
        float*       orow = out_h + (size_t)node * HD;
        #pragma unroll
        for (int n = 0; n < 8; ++n) {
            const int f = n*16 + col;
            orow[f] = hr[f] + acc[n][i] + bn2[f];
        }
    }
}

extern "C" void kernel_launch(void* const* d_in, const int* in_sizes, int n_in,
                              void* d_out, int out_size, void* d_ws, size_t ws_size,
                              hipStream_t stream)
{
    const int*   src    = (const int*)  d_in[0];
    const int*   dst    = (const int*)  d_in[1];
    const float* h      = (const float*)d_in[2];
    const float* coords = (const float*)d_in[3];
    const float* a      = (const float*)d_in[4];
    const float* Wc1    = (const float*)d_in[5];
    const float* bc1    = (const float*)d_in[6];
    const float* Wc2    = (const float*)d_in[7];
    const float* bc2    = (const float*)d_in[8];
    const float* Wc3    = (const float*)d_in[9];
    const float* We1    = (const float*)d_in[10];
    const float* be1    = (const float*)d_in[11];
    const float* We2    = (const float*)d_in[12];
    const float* be2    = (const float*)d_in[13];
    const float* Watt   = (const float*)d_in[14];
    const float* batt   = (const float*)d_in[15];
    const float* Wn1    = (const float*)d_in[16];
    const float* bn1    = (const float*)d_in[17];
    const float* Wn2    = (const float*)d_in[18];
    const float* bn2    = (const float*)d_in[19];

    const int E = in_sizes[0];
    const int N = in_sizes[2] / HD;

    float* out_h = (float*)d_out;
    float* out_x = out_h + (size_t)N * HD;
    unsigned short* wsb = (unsigned short*)d_ws;

    hipMemsetAsync(d_out, 0, (size_t)out_size * sizeof(float), stream);

    prep_weights<<<dim3(WS_ELEMS / 256), dim3(256), 0, stream>>>(
        Wc1, We1, Wc2, We2, Wn1, Wn2, wsb);

    edge_kernel<<<dim3(E / MT), dim3(256), 0, stream>>>(
        src, dst, h, coords, a,
        bc1, bc2, Wc3, be1, be2, Watt, batt,
        wsb, out_h, out_x);

    node_kernel<<<dim3(N / MT), dim3(256), 0, stream>>>(
        h, coords, bn1, bn2, wsb, out_h, out_x);
}